// Round 1
// baseline (1735.078 us; speedup 1.0000x reference)
//
#include <hip/hip_runtime.h>
#include <cstdint>

#define BATCH 4
#define CPD 64
#define RES 64
#define NS 131072
#define NF 512
#define FS 2048
#define HID 16

// ---------------------------------------------------------------------------
// K1: damping + sequential scan.  out[0]=f[0]; out[i]=(f[i]+out[i-1])*d[i]
// One block per batch; stage (forces, dmod) chunks into LDS with coalesced
// loads, then wave 0 (lane = channel) runs the serial recurrence.
// Writes damped in frame-major layout (B, NF, CPD) for K2.
// ---------------------------------------------------------------------------
__global__ __launch_bounds__(256) void k_scan(const float* __restrict__ forces,
                                              const float* __restrict__ dmod,
                                              const float* __restrict__ dparam,
                                              float* __restrict__ damped_t) {
  __shared__ float f_lds[64][129];  // +1 pad: scan reads stride-129 -> conflict-free
  __shared__ float d_lds[64][129];
  const int b = blockIdx.x;
  const int tid = threadIdx.x;
  float dbase = 0.f, carry = 0.f;
  if (tid < 64) {
    float dp = dparam[tid];                       // damping_param (1,CPD,1)
    dbase = 0.5f + (0.9999f - 0.5f) / (1.f + expf(-dp));
  }
  for (int ch = 0; ch < 4; ++ch) {
    const int t0 = ch * 128;
    __syncthreads();
    for (int idx = tid; idx < 64 * 128; idx += 256) {
      int c = idx >> 7, tl = idx & 127;
      f_lds[c][tl] = forces[(b * CPD + c) * NF + t0 + tl];
      d_lds[c][tl] = dmod[(b * CPD + c) * NF + t0 + tl];
    }
    __syncthreads();
    if (tid < 64) {
      const int c = tid;
      for (int tl = 0; tl < 128; ++tl) {
        float d = dbase - fabsf(d_lds[c][tl]);
        d = fminf(fmaxf(d, 0.f), 1.f);
        float f = f_lds[c][tl];
        float out = (ch == 0 && tl == 0) ? f : (f + carry) * d;
        carry = out;
        damped_t[(b * NF + t0 + tl) * CPD + c] = out;
      }
    }
  }
}

// ---------------------------------------------------------------------------
// K2: hypernetwork (64->16 leaky relu -> 64*64), per-frame routing matrix,
// routed = x^T W(x), to_ctrl = routed @ to_control.
// Block = 4 frames x 64 res-threads (each wave is one frame).
// ---------------------------------------------------------------------------
__global__ __launch_bounds__(256) void k_hyper(const float* __restrict__ damped_t,
                                               const float* __restrict__ routing,
                                               const float* __restrict__ W1,
                                               const float* __restrict__ b1,
                                               const float* __restrict__ W2,
                                               const float* __restrict__ b2,
                                               const float* __restrict__ to_control,
                                               float* __restrict__ routed,
                                               float* __restrict__ to_ctrl) {
  __shared__ float xs[4][64];
  __shared__ float hs[4][16];
  __shared__ float rs[4][64];
  const int blk = blockIdx.x;
  const int b = blk >> 7;                 // NF/4 = 128 blocks per batch
  const int t0 = (blk & 127) * 4;
  const int lt = threadIdx.x >> 6;        // local frame 0..3
  const int d = threadIdx.x & 63;         // res / cpd lane
  const int t = t0 + lt;

  xs[lt][d] = damped_t[(b * NF + t) * CPD + d];
  __syncthreads();
  if (d < HID) {
    float a = b1[d];
    for (int c = 0; c < CPD; ++c) a = fmaf(xs[lt][c], W1[c * HID + d], a);
    hs[lt][d] = a > 0.f ? a : 0.2f * a;   // leaky relu 0.2
  }
  __syncthreads();
  float hreg[HID];
#pragma unroll
  for (int j = 0; j < HID; ++j) hreg[j] = hs[lt][j];

  float acc = 0.f;
  for (int c = 0; c < CPD; ++c) {
    float w = routing[c * RES + d] + b2[c * RES + d];
    const float* w2p = W2 + c * RES + d;  // W2 (HID, CPD*RES)
#pragma unroll
    for (int j = 0; j < HID; ++j) w = fmaf(hreg[j], w2p[j * (CPD * RES)], w);
    acc = fmaf(xs[lt][c], w, acc);
  }
  routed[(b * RES + d) * NF + t] = acc;
  rs[lt][d] = acc;
  __syncthreads();
  float tc = 0.f;
  for (int q = 0; q < RES; ++q) tc = fmaf(rs[lt][q], to_control[q * CPD + d], tc);
  to_ctrl[(b * CPD + d) * NF + t] = tc;
}

// ---------------------------------------------------------------------------
// K3: fused upsample(x256 linear) * noise -> 2048-tap causal FIR.
// Block = one 2048-output segment of one (b, r) channel. Energy tile
// (2048 history + 2048 current) built in LDS (pad 1-per-8: addr=9*(l>>3)+(l&7)
// so stride-8 lane reads land on distinct banks). Sliding 8-wide register
// window: per tap = 1 LDS read + 8 FMAs -> VALU-bound.
// ---------------------------------------------------------------------------
__global__ __launch_bounds__(256) void k_conv(const float* __restrict__ routed,
                                              const float* __restrict__ noise,
                                              const float* __restrict__ filters,
                                              float* __restrict__ outp) {
  __shared__ float e_lds[4608];  // 4096 + 512 pads
  __shared__ float f_lds[FS];
  const int blk = blockIdx.x;
  const int seg = blk & 63;
  const int r = (blk >> 6) & 63;
  const int b = blk >> 12;
  const int n0 = seg * 2048;
  const int tid = threadIdx.x;
  const float* rp = routed + (b * RES + r) * NF;
  const float* npz = noise + (size_t)(b * RES + r) * NS;

  for (int k = tid; k < FS; k += 256) f_lds[k] = filters[r * FS + k];
  for (int l = tid; l < 4096; l += 256) {
    int n = n0 - 2048 + l;
    float e = 0.f;
    if (n >= 0) {
      float pos = ((float)n + 0.5f) * (1.f / 256.f) - 0.5f;
      pos = fminf(fmaxf(pos, 0.f), 511.f);
      float fi = floorf(pos);
      int i0 = (int)fi;
      int i1 = i0 + 1; if (i1 > 511) i1 = 511;
      float fr = pos - fi;
      float u = rp[i0] * (1.f - fr) + rp[i1] * fr;
      e = u * npz[n];
    }
    e_lds[9 * (l >> 3) + (l & 7)] = e;
  }
  __syncthreads();

  float acc[8] = {0.f, 0.f, 0.f, 0.f, 0.f, 0.f, 0.f, 0.f};
  float win[8];
#pragma unroll
  for (int j = 0; j < 8; ++j) win[j] = e_lds[9 * (tid + 256) + j];  // e[m0+j]
  int A = 9 * (tid + 255) + 7;  // padded addr of e[m0-1] (first slide value)

  for (int k = 0; k < FS; k += 8) {
#pragma unroll
    for (int kk = 0; kk < 8; ++kk) {
      const float fk = f_lds[k + kk];
#pragma unroll
      for (int j = 0; j < 8; ++j) acc[j] = fmaf(fk, win[j], acc[j]);
      const float nv = e_lds[A - kk];   // e[m0 - (k+kk) - 1]
#pragma unroll
      for (int j = 7; j > 0; --j) win[j] = win[j - 1];
      win[0] = nv;
    }
    A -= 9;
  }

  size_t off = (size_t)(b * RES + r) * NS + n0 + tid * 8;
  *(float4*)(outp + off) = make_float4(acc[0], acc[1], acc[2], acc[3]);
  *(float4*)(outp + off + 4) = make_float4(acc[4], acc[5], acc[6], acc[7]);
}

// ---------------------------------------------------------------------------
extern "C" void kernel_launch(void* const* d_in, const int* in_sizes, int n_in,
                              void* d_out, int out_size, void* d_ws, size_t ws_size,
                              hipStream_t stream) {
  const float* forces     = (const float*)d_in[0];
  const float* dmod       = (const float*)d_in[1];
  const float* noise      = (const float*)d_in[2];
  const float* dparam     = (const float*)d_in[3];
  const float* routing    = (const float*)d_in[4];
  const float* W1         = (const float*)d_in[5];
  const float* b1         = (const float*)d_in[6];
  const float* W2         = (const float*)d_in[7];
  const float* b2         = (const float*)d_in[8];
  const float* filters    = (const float*)d_in[9];
  const float* to_control = (const float*)d_in[10];

  float* out = (float*)d_out;
  float* to_ctrl = out;                                  // (B,CPD,NF) = 131072
  float* reso = out + BATCH * CPD * NF;                  // (B,RES,NS)

  float* damped_t = (float*)d_ws;                        // (B,NF,CPD) 512 KB
  float* routed = damped_t + BATCH * NF * CPD;           // (B,RES,NF) 512 KB

  k_scan<<<BATCH, 256, 0, stream>>>(forces, dmod, dparam, damped_t);
  k_hyper<<<BATCH * NF / 4, 256, 0, stream>>>(damped_t, routing, W1, b1, W2, b2,
                                              to_control, routed, to_ctrl);
  k_conv<<<BATCH * RES * (NS / 2048), 256, 0, stream>>>(routed, noise, filters, reso);
}

// Round 2
// 474.214 us; speedup vs baseline: 3.6588x; 3.6588x over previous
//
#include <hip/hip_runtime.h>
#include <cstdint>

#define BATCH 4
#define CPD 64
#define RES 64
#define NS 131072
#define NF 512
#define FS 2048
#define HID 16

typedef __attribute__((ext_vector_type(8))) short s16x8;
typedef __attribute__((ext_vector_type(16))) float f32x16;

__device__ inline unsigned short f2bf(float f) {
  unsigned u = __float_as_uint(f);
  unsigned r = (u + 0x7FFFu + ((u >> 16) & 1u)) >> 16;
  return (unsigned short)r;
}
__device__ inline float bf2f(unsigned short h) {
  return __uint_as_float(((unsigned)h) << 16);
}

// ---------------------------------------------------------------------------
// K1: damping + sequential scan (unchanged from round 1; passed, tiny cost)
// ---------------------------------------------------------------------------
__global__ __launch_bounds__(256) void k_scan(const float* __restrict__ forces,
                                              const float* __restrict__ dmod,
                                              const float* __restrict__ dparam,
                                              float* __restrict__ damped_t) {
  __shared__ float f_lds[64][129];
  __shared__ float d_lds[64][129];
  const int b = blockIdx.x;
  const int tid = threadIdx.x;
  float dbase = 0.f, carry = 0.f;
  if (tid < 64) {
    float dp = dparam[tid];
    dbase = 0.5f + (0.9999f - 0.5f) / (1.f + expf(-dp));
  }
  for (int ch = 0; ch < 4; ++ch) {
    const int t0 = ch * 128;
    __syncthreads();
    for (int idx = tid; idx < 64 * 128; idx += 256) {
      int c = idx >> 7, tl = idx & 127;
      f_lds[c][tl] = forces[(b * CPD + c) * NF + t0 + tl];
      d_lds[c][tl] = dmod[(b * CPD + c) * NF + t0 + tl];
    }
    __syncthreads();
    if (tid < 64) {
      const int c = tid;
      for (int tl = 0; tl < 128; ++tl) {
        float d = dbase - fabsf(d_lds[c][tl]);
        d = fminf(fmaxf(d, 0.f), 1.f);
        float f = f_lds[c][tl];
        float out = (ch == 0 && tl == 0) ? f : (f + carry) * d;
        carry = out;
        damped_t[(b * NF + t0 + tl) * CPD + c] = out;
      }
    }
  }
}

// ---------------------------------------------------------------------------
// K2: hypernetwork + routing einsum + to_ctrl (unchanged)
// ---------------------------------------------------------------------------
__global__ __launch_bounds__(256) void k_hyper(const float* __restrict__ damped_t,
                                               const float* __restrict__ routing,
                                               const float* __restrict__ W1,
                                               const float* __restrict__ b1,
                                               const float* __restrict__ W2,
                                               const float* __restrict__ b2,
                                               const float* __restrict__ to_control,
                                               float* __restrict__ routed,
                                               float* __restrict__ to_ctrl) {
  __shared__ float xs[4][64];
  __shared__ float hs[4][16];
  __shared__ float rs[4][64];
  const int blk = blockIdx.x;
  const int b = blk >> 7;
  const int t0 = (blk & 127) * 4;
  const int lt = threadIdx.x >> 6;
  const int d = threadIdx.x & 63;
  const int t = t0 + lt;

  xs[lt][d] = damped_t[(b * NF + t) * CPD + d];
  __syncthreads();
  if (d < HID) {
    float a = b1[d];
    for (int c = 0; c < CPD; ++c) a = fmaf(xs[lt][c], W1[c * HID + d], a);
    hs[lt][d] = a > 0.f ? a : 0.2f * a;
  }
  __syncthreads();
  float hreg[HID];
#pragma unroll
  for (int j = 0; j < HID; ++j) hreg[j] = hs[lt][j];

  float acc = 0.f;
  for (int c = 0; c < CPD; ++c) {
    float w = routing[c * RES + d] + b2[c * RES + d];
    const float* w2p = W2 + c * RES + d;
#pragma unroll
    for (int j = 0; j < HID; ++j) w = fmaf(hreg[j], w2p[j * (CPD * RES)], w);
    acc = fmaf(xs[lt][c], w, acc);
  }
  routed[(b * RES + d) * NF + t] = acc;
  rs[lt][d] = acc;
  __syncthreads();
  float tc = 0.f;
  for (int q = 0; q < RES; ++q) tc = fmaf(rs[lt][q], to_control[q * CPD + d], tc);
  to_ctrl[(b * CPD + d) * NF + t] = tc;
}

// ---------------------------------------------------------------------------
// K3: conv as implicit block-Hankel GEMM on MFMA (bf16 hi/lo split, fp32 acc).
//
//   out[nb+32m+n] = sum_k f[k] e[nb+32m+n-k],  e = upsample(routed)*noise
//   A[m][i] = e[nb-k0+32m+8-i]   (i in [0,16))  -> reversed-e LDS array
//   B[i][n] = f[k0+n+i-8]                       -> 4 shifted pair-copies
//   k0 = -32 + 16*s, s = 0..130  (full tap coverage, each k exactly once)
//
// Block: 4 waves x 2 tiles (32x32 C each) = 8192 outputs per block.
// LDS: er_h/er_l reversed energy (padded +1 granule per 8 for bank balance),
//      fcp[4] = filter (fh,fl) pair copies shifted by p for 16B alignment.
// ---------------------------------------------------------------------------
#define ER_N 10256          // staged energy samples per block
#define ER_US 11536         // ushort slots incl. pad granules
#define FC_N 2132           // dwords per filter copy

__global__ __launch_bounds__(256, 2) void k_conv(const float* __restrict__ routed,
                                                 const float* __restrict__ noise,
                                                 const float* __restrict__ filters,
                                                 float* __restrict__ outp) {
  __shared__ __align__(16) unsigned short er_h[ER_US];
  __shared__ __align__(16) unsigned short er_l[ER_US];
  __shared__ __align__(16) unsigned fcp[4][FC_N];

  const int tid = threadIdx.x;
  const int seg = blockIdx.x & 15;
  const int r = (blockIdx.x >> 4) & 63;
  const int b = blockIdx.x >> 10;
  const int NB = seg * 8192;
  const int E0 = NB + 8200;          // er[x] = e[E0 - x]
  const int chan = b * RES + r;
  const float* rp = routed + chan * NF;
  const float* npz = noise + (size_t)chan * NS;

  // ---- filter staging: 4 shifted copies of (fh,fl) pairs ----
  for (int q = tid; q < FC_N; q += 256) {
#pragma unroll
    for (int p = 0; p < 4; ++p) {
      int fidx = q + p - 40;
      float fv = (fidx >= 0 && fidx < FS) ? filters[r * FS + fidx] : 0.f;
      unsigned short fh = f2bf(fv);
      unsigned short fl = f2bf(fv - bf2f(fh));
      fcp[p][q] = (unsigned)fh | ((unsigned)fl << 16);
    }
  }
  // ---- energy staging: reversed, hi/lo split, bank-balancing pad ----
  for (int x = tid; x < ER_N; x += 256) {
    int n = E0 - x;
    float e = 0.f;
    if (n >= 0 && n < NS) {
      float pos = ((float)n + 0.5f) * (1.f / 256.f) - 0.5f;
      pos = fminf(fmaxf(pos, 0.f), 511.f);
      float fi = floorf(pos);
      int i0 = (int)fi;
      int i1 = min(i0 + 1, 511);
      float fr = pos - fi;
      float u = rp[i0] * (1.f - fr) + rp[i1] * fr;
      e = u * npz[n];
    }
    unsigned short eh = f2bf(e);
    unsigned short el = f2bf(e - bf2f(eh));
    int c = x >> 3;
    int addr = ((c + (c >> 3)) << 3) + (x & 7);   // ushort index
    er_h[addr] = eh;
    er_l[addr] = el;
  }
  __syncthreads();

  const int w = tid >> 6;
  const int l = tid & 63;
  const int m = l & 31;     // A row == B col == C col lane index
  const int blkh = l >> 5;  // k-half
  const int p = m & 3;

  const int t0 = 2 * w, t1 = 2 * w + 1;
  int ct0 = ((8192 - 1024 * t0) - 32 - 32 * m + 8 * blkh) >> 3;  // granule idx, k0=-32
  int ct1 = ((8192 - 1024 * t1) - 32 - 32 * m + 8 * blkh) >> 3;
  int offB = (m - p) + 8 * blkh;   // dword offset into fcp[p], k0=-32

  f32x16 acc0, acc1;
#pragma unroll
  for (int i = 0; i < 16; ++i) { acc0[i] = 0.f; acc1[i] = 0.f; }

  const unsigned* fp = fcp[p];

  for (int s = 0; s < 131; ++s) {
    uint4 q0 = *(const uint4*)(fp + offB);
    uint4 q1 = *(const uint4*)(fp + offB + 4);
    union { unsigned u[4]; s16x8 v; } BH, BL;
    BH.u[0] = __builtin_amdgcn_perm(q0.y, q0.x, 0x05040100u);
    BH.u[1] = __builtin_amdgcn_perm(q0.w, q0.z, 0x05040100u);
    BH.u[2] = __builtin_amdgcn_perm(q1.y, q1.x, 0x05040100u);
    BH.u[3] = __builtin_amdgcn_perm(q1.w, q1.z, 0x05040100u);
    BL.u[0] = __builtin_amdgcn_perm(q0.y, q0.x, 0x07060302u);
    BL.u[1] = __builtin_amdgcn_perm(q0.w, q0.z, 0x07060302u);
    BL.u[2] = __builtin_amdgcn_perm(q1.y, q1.x, 0x07060302u);
    BL.u[3] = __builtin_amdgcn_perm(q1.w, q1.z, 0x07060302u);

    {
      int ab = (ct0 + (ct0 >> 3)) << 4;
      union { uint4 u; s16x8 v; } AH, AL;
      AH.u = *(const uint4*)((const char*)er_h + ab);
      AL.u = *(const uint4*)((const char*)er_l + ab);
      acc0 = __builtin_amdgcn_mfma_f32_32x32x16_bf16(AH.v, BH.v, acc0, 0, 0, 0);
      acc0 = __builtin_amdgcn_mfma_f32_32x32x16_bf16(AL.v, BH.v, acc0, 0, 0, 0);
      acc0 = __builtin_amdgcn_mfma_f32_32x32x16_bf16(AH.v, BL.v, acc0, 0, 0, 0);
      ct0 += 2;
    }
    {
      int ab = (ct1 + (ct1 >> 3)) << 4;
      union { uint4 u; s16x8 v; } AH, AL;
      AH.u = *(const uint4*)((const char*)er_h + ab);
      AL.u = *(const uint4*)((const char*)er_l + ab);
      acc1 = __builtin_amdgcn_mfma_f32_32x32x16_bf16(AH.v, BH.v, acc1, 0, 0, 0);
      acc1 = __builtin_amdgcn_mfma_f32_32x32x16_bf16(AL.v, BH.v, acc1, 0, 0, 0);
      acc1 = __builtin_amdgcn_mfma_f32_32x32x16_bf16(AH.v, BL.v, acc1, 0, 0, 0);
      ct1 += 2;
    }
    offB += 16;
  }

  // ---- C store: col = lane&31, row = (reg&3) + 8*(reg>>2) + 4*(lane>>5) ----
  float* po0 = outp + (size_t)chan * NS + NB + t0 * 1024;
  float* po1 = outp + (size_t)chan * NS + NB + t1 * 1024;
#pragma unroll
  for (int rg = 0; rg < 16; ++rg) {
    int row = (rg & 3) + 8 * (rg >> 2) + 4 * blkh;
    po0[32 * row + m] = acc0[rg];
    po1[32 * row + m] = acc1[rg];
  }
}

// ---------------------------------------------------------------------------
extern "C" void kernel_launch(void* const* d_in, const int* in_sizes, int n_in,
                              void* d_out, int out_size, void* d_ws, size_t ws_size,
                              hipStream_t stream) {
  const float* forces     = (const float*)d_in[0];
  const float* dmod       = (const float*)d_in[1];
  const float* noise      = (const float*)d_in[2];
  const float* dparam     = (const float*)d_in[3];
  const float* routing    = (const float*)d_in[4];
  const float* W1         = (const float*)d_in[5];
  const float* b1         = (const float*)d_in[6];
  const float* W2         = (const float*)d_in[7];
  const float* b2         = (const float*)d_in[8];
  const float* filters    = (const float*)d_in[9];
  const float* to_control = (const float*)d_in[10];

  float* out = (float*)d_out;
  float* to_ctrl = out;                                  // (B,CPD,NF)
  float* reso = out + BATCH * CPD * NF;                  // (B,RES,NS)

  float* damped_t = (float*)d_ws;                        // (B,NF,CPD)
  float* routed = damped_t + BATCH * NF * CPD;           // (B,RES,NF)

  k_scan<<<BATCH, 256, 0, stream>>>(forces, dmod, dparam, damped_t);
  k_hyper<<<BATCH * NF / 4, 256, 0, stream>>>(damped_t, routing, W1, b1, W2, b2,
                                              to_control, routed, to_ctrl);
  k_conv<<<BATCH * RES * (NS / 8192), 256, 0, stream>>>(routed, noise, filters, reso);
}

// Round 3
// 448.929 us; speedup vs baseline: 3.8649x; 1.0563x over previous
//
#include <hip/hip_runtime.h>
#include <cstdint>

#define BATCH 4
#define CPD 64
#define RES 64
#define NS 131072
#define NF 512
#define FS 2048
#define HID 16

typedef __attribute__((ext_vector_type(8))) short s16x8;
typedef __attribute__((ext_vector_type(16))) float f32x16;

__device__ inline unsigned short f2bf(float f) {
  unsigned u = __float_as_uint(f);
  unsigned r = (u + 0x7FFFu + ((u >> 16) & 1u)) >> 16;
  return (unsigned short)r;
}
__device__ inline float bf2f(unsigned short h) {
  return __uint_as_float(((unsigned)h) << 16);
}

// ---------------------------------------------------------------------------
// K1: damping + sequential scan (unchanged; tiny cost, passed)
// ---------------------------------------------------------------------------
__global__ __launch_bounds__(256) void k_scan(const float* __restrict__ forces,
                                              const float* __restrict__ dmod,
                                              const float* __restrict__ dparam,
                                              float* __restrict__ damped_t) {
  __shared__ float f_lds[64][129];
  __shared__ float d_lds[64][129];
  const int b = blockIdx.x;
  const int tid = threadIdx.x;
  float dbase = 0.f, carry = 0.f;
  if (tid < 64) {
    float dp = dparam[tid];
    dbase = 0.5f + (0.9999f - 0.5f) / (1.f + expf(-dp));
  }
  for (int ch = 0; ch < 4; ++ch) {
    const int t0 = ch * 128;
    __syncthreads();
    for (int idx = tid; idx < 64 * 128; idx += 256) {
      int c = idx >> 7, tl = idx & 127;
      f_lds[c][tl] = forces[(b * CPD + c) * NF + t0 + tl];
      d_lds[c][tl] = dmod[(b * CPD + c) * NF + t0 + tl];
    }
    __syncthreads();
    if (tid < 64) {
      const int c = tid;
      for (int tl = 0; tl < 128; ++tl) {
        float d = dbase - fabsf(d_lds[c][tl]);
        d = fminf(fmaxf(d, 0.f), 1.f);
        float f = f_lds[c][tl];
        float out = (ch == 0 && tl == 0) ? f : (f + carry) * d;
        carry = out;
        damped_t[(b * NF + t0 + tl) * CPD + c] = out;
      }
    }
  }
}

// ---------------------------------------------------------------------------
// K2: hypernetwork + routing einsum + to_ctrl (unchanged)
// ---------------------------------------------------------------------------
__global__ __launch_bounds__(256) void k_hyper(const float* __restrict__ damped_t,
                                               const float* __restrict__ routing,
                                               const float* __restrict__ W1,
                                               const float* __restrict__ b1,
                                               const float* __restrict__ W2,
                                               const float* __restrict__ b2,
                                               const float* __restrict__ to_control,
                                               float* __restrict__ routed,
                                               float* __restrict__ to_ctrl) {
  __shared__ float xs[4][64];
  __shared__ float hs[4][16];
  __shared__ float rs[4][64];
  const int blk = blockIdx.x;
  const int b = blk >> 7;
  const int t0 = (blk & 127) * 4;
  const int lt = threadIdx.x >> 6;
  const int d = threadIdx.x & 63;
  const int t = t0 + lt;

  xs[lt][d] = damped_t[(b * NF + t) * CPD + d];
  __syncthreads();
  if (d < HID) {
    float a = b1[d];
    for (int c = 0; c < CPD; ++c) a = fmaf(xs[lt][c], W1[c * HID + d], a);
    hs[lt][d] = a > 0.f ? a : 0.2f * a;
  }
  __syncthreads();
  float hreg[HID];
#pragma unroll
  for (int j = 0; j < HID; ++j) hreg[j] = hs[lt][j];

  float acc = 0.f;
  for (int c = 0; c < CPD; ++c) {
    float w = routing[c * RES + d] + b2[c * RES + d];
    const float* w2p = W2 + c * RES + d;
#pragma unroll
    for (int j = 0; j < HID; ++j) w = fmaf(hreg[j], w2p[j * (CPD * RES)], w);
    acc = fmaf(xs[lt][c], w, acc);
  }
  routed[(b * RES + d) * NF + t] = acc;
  rs[lt][d] = acc;
  __syncthreads();
  float tc = 0.f;
  for (int q = 0; q < RES; ++q) tc = fmaf(rs[lt][q], to_control[q * CPD + d], tc);
  to_ctrl[(b * CPD + d) * NF + t] = tc;
}

// ---------------------------------------------------------------------------
// K3: block-Hankel GEMM conv, round-3 structure.
// 512 threads (8 waves) x 4 tiles/wave = 32768 outputs per block.
// er_h/er_l: reversed energy, XOR-swizzled granules sig(g)=g^((g>>3)&7)
//   -> A-read pattern (g = C - 4*row + h) hits 8 lanes/bank-quad (minimum).
// fcp: single filter copy of (fh,fl) pair dwords, per-dword clamped reads
//   (index >= 2088 -> zero region) -> ds_read2_b32-class accesses.
// ---------------------------------------------------------------------------
#define ER_G 4360           // granules (16B each) incl swizzle round-up
#define ER_N 34832          // staged samples: x = 0..34831
#define FC_N 2092           // filter pair dwords (>=2088 all zero)

__global__ __launch_bounds__(512, 2) void k_conv(const float* __restrict__ routed,
                                                 const float* __restrict__ noise,
                                                 const float* __restrict__ filters,
                                                 float* __restrict__ outp) {
  __shared__ __align__(16) unsigned short er_h[ER_G * 8];
  __shared__ __align__(16) unsigned short er_l[ER_G * 8];
  __shared__ __align__(16) unsigned fcp[FC_N];

  const int tid = threadIdx.x;
  const int seg = blockIdx.x & 3;
  const int r = (blockIdx.x >> 2) & 63;
  const int b = blockIdx.x >> 8;
  const int NB = seg * 32768;
  const int E0 = NB + 32776;          // er[x] = e[E0 - x]
  const int chan = b * RES + r;
  const float* rp = routed + chan * NF;
  const float* npz = noise + (size_t)chan * NS;

  // ---- filter staging: single (fh,fl) pair copy, zero outside [0,FS) ----
  for (int q = tid; q < FC_N; q += 512) {
    int fidx = q - 40;
    float fv = (fidx >= 0 && fidx < FS) ? filters[r * FS + fidx] : 0.f;
    unsigned short fh = f2bf(fv);
    unsigned short fl = f2bf(fv - bf2f(fh));
    fcp[q] = (unsigned)fh | ((unsigned)fl << 16);
  }

  // ---- energy staging: pairs (x, x+1), b32 writes, XOR-swizzled layout ----
  unsigned* erh32 = (unsigned*)er_h;
  unsigned* erl32 = (unsigned*)er_l;
  for (int x2 = tid; x2 < ER_N / 2; x2 += 512) {
    int x = 2 * x2;
    unsigned short eh[2], el[2];
#pragma unroll
    for (int k = 0; k < 2; ++k) {
      int n = E0 - x - k;
      float e = 0.f;
      if (n >= 0 && n < NS) {
        float pos = ((float)n + 0.5f) * (1.f / 256.f) - 0.5f;
        pos = fminf(fmaxf(pos, 0.f), 511.f);
        float fi = floorf(pos);
        int i0 = (int)fi;
        int i1 = min(i0 + 1, 511);
        float fr = pos - fi;
        float u = rp[i0] * (1.f - fr) + rp[i1] * fr;
        e = u * npz[n];
      }
      eh[k] = f2bf(e);
      el[k] = f2bf(e - bf2f(eh[k]));
    }
    int g = x >> 3;
    int sig = g ^ ((g >> 3) & 7);
    int dw = sig * 4 + ((x & 7) >> 1);
    erh32[dw] = (unsigned)eh[0] | ((unsigned)eh[1] << 16);
    erl32[dw] = (unsigned)el[0] | ((unsigned)el[1] << 16);
  }
  __syncthreads();

  const int w = tid >> 6;
  const int l = tid & 63;
  const int row = l & 31;   // A-row == B-col lane index
  const int h = l >> 5;     // k-half

  // A granule bases per tile: g = 4092 - 128*T - 4*row + h + 2*s, T = 4w+tau
  const int gb0 = 4092 - 128 * (4 * w + 0) - 4 * row + h;
  const int gb1 = gb0 - 128;
  const int gb2 = gb0 - 256;
  const int gb3 = gb0 - 384;
  int qb = row + 8 * h;     // B base dword (+16 per step)

  f32x16 acc0, acc1, acc2, acc3;
#pragma unroll
  for (int i = 0; i < 16; ++i) { acc0[i] = 0.f; acc1[i] = 0.f; acc2[i] = 0.f; acc3[i] = 0.f; }

  for (int s = 0; s < 131; ++s) {
    // ---- B fragment: 4 clamped pair-reads -> 8 dwords -> perm split ----
    int qc0 = min(qb + 0, 2090);
    int qc2 = min(qb + 2, 2090);
    int qc4 = min(qb + 4, 2090);
    int qc6 = min(qb + 6, 2090);
    unsigned qd0 = fcp[qc0], qd1 = fcp[qc0 + 1];
    unsigned qd2 = fcp[qc2], qd3 = fcp[qc2 + 1];
    unsigned qd4 = fcp[qc4], qd5 = fcp[qc4 + 1];
    unsigned qd6 = fcp[qc6], qd7 = fcp[qc6 + 1];
    union { unsigned u[4]; s16x8 v; } BH, BL;
    BH.u[0] = __builtin_amdgcn_perm(qd1, qd0, 0x05040100u);
    BH.u[1] = __builtin_amdgcn_perm(qd3, qd2, 0x05040100u);
    BH.u[2] = __builtin_amdgcn_perm(qd5, qd4, 0x05040100u);
    BH.u[3] = __builtin_amdgcn_perm(qd7, qd6, 0x05040100u);
    BL.u[0] = __builtin_amdgcn_perm(qd1, qd0, 0x07060302u);
    BL.u[1] = __builtin_amdgcn_perm(qd3, qd2, 0x07060302u);
    BL.u[2] = __builtin_amdgcn_perm(qd5, qd4, 0x07060302u);
    BL.u[3] = __builtin_amdgcn_perm(qd7, qd6, 0x07060302u);

    const int s2 = 2 * s;
#define TILE3(ACC, GB)                                                        \
    {                                                                         \
      int g = (GB) + s2;                                                      \
      int ab = (g ^ ((g >> 3) & 7)) << 4;                                     \
      union { uint4 u; s16x8 v; } AH, AL;                                     \
      AH.u = *(const uint4*)((const char*)er_h + ab);                         \
      AL.u = *(const uint4*)((const char*)er_l + ab);                         \
      ACC = __builtin_amdgcn_mfma_f32_32x32x16_bf16(AH.v, BH.v, ACC, 0, 0, 0);\
      ACC = __builtin_amdgcn_mfma_f32_32x32x16_bf16(AL.v, BH.v, ACC, 0, 0, 0);\
      ACC = __builtin_amdgcn_mfma_f32_32x32x16_bf16(AH.v, BL.v, ACC, 0, 0, 0);\
    }
    TILE3(acc0, gb0)
    TILE3(acc1, gb1)
    TILE3(acc2, gb2)
    TILE3(acc3, gb3)
#undef TILE3
    qb += 16;
  }

  // ---- C store: col = row-lane, crow = (rg&3) + 8*(rg>>2) + 4*h ----
  float* base = outp + (size_t)chan * NS + NB;
#define STORE(ACC, TAU)                                                       \
  {                                                                           \
    float* po = base + 1024 * (4 * w + (TAU));                                \
    _Pragma("unroll")                                                         \
    for (int rg = 0; rg < 16; ++rg) {                                         \
      int crow = (rg & 3) + 8 * (rg >> 2) + 4 * h;                            \
      po[32 * crow + row] = ACC[rg];                                          \
    }                                                                         \
  }
  STORE(acc0, 0)
  STORE(acc1, 1)
  STORE(acc2, 2)
  STORE(acc3, 3)
#undef STORE
}

// ---------------------------------------------------------------------------
extern "C" void kernel_launch(void* const* d_in, const int* in_sizes, int n_in,
                              void* d_out, int out_size, void* d_ws, size_t ws_size,
                              hipStream_t stream) {
  const float* forces     = (const float*)d_in[0];
  const float* dmod       = (const float*)d_in[1];
  const float* noise      = (const float*)d_in[2];
  const float* dparam     = (const float*)d_in[3];
  const float* routing    = (const float*)d_in[4];
  const float* W1         = (const float*)d_in[5];
  const float* b1         = (const float*)d_in[6];
  const float* W2         = (const float*)d_in[7];
  const float* b2         = (const float*)d_in[8];
  const float* filters    = (const float*)d_in[9];
  const float* to_control = (const float*)d_in[10];

  float* out = (float*)d_out;
  float* to_ctrl = out;                                  // (B,CPD,NF)
  float* reso = out + BATCH * CPD * NF;                  // (B,RES,NS)

  float* damped_t = (float*)d_ws;                        // (B,NF,CPD)
  float* routed = damped_t + BATCH * NF * CPD;           // (B,RES,NF)

  k_scan<<<BATCH, 256, 0, stream>>>(forces, dmod, dparam, damped_t);
  k_hyper<<<BATCH * NF / 4, 256, 0, stream>>>(damped_t, routing, W1, b1, W2, b2,
                                              to_control, routed, to_ctrl);
  k_conv<<<BATCH * RES * (NS / 32768), 512, 0, stream>>>(routed, noise, filters, reso);
}

// Round 4
// 235.107 us; speedup vs baseline: 7.3799x; 1.9095x over previous
//
#include <hip/hip_runtime.h>
#include <cstdint>

#define BATCH 4
#define CPD 64
#define RES 64
#define NS 131072
#define NF 512
#define FS 2048
#define HID 16

typedef _Float16 __attribute__((ext_vector_type(8))) f16x8;
typedef float __attribute__((ext_vector_type(16))) f32x16;

// ---------------------------------------------------------------------------
// K1: damping + sequential scan (unchanged; tiny cost, passed)
// ---------------------------------------------------------------------------
__global__ __launch_bounds__(256) void k_scan(const float* __restrict__ forces,
                                              const float* __restrict__ dmod,
                                              const float* __restrict__ dparam,
                                              float* __restrict__ damped_t) {
  __shared__ float f_lds[64][129];
  __shared__ float d_lds[64][129];
  const int b = blockIdx.x;
  const int tid = threadIdx.x;
  float dbase = 0.f, carry = 0.f;
  if (tid < 64) {
    float dp = dparam[tid];
    dbase = 0.5f + (0.9999f - 0.5f) / (1.f + expf(-dp));
  }
  for (int ch = 0; ch < 4; ++ch) {
    const int t0 = ch * 128;
    __syncthreads();
    for (int idx = tid; idx < 64 * 128; idx += 256) {
      int c = idx >> 7, tl = idx & 127;
      f_lds[c][tl] = forces[(b * CPD + c) * NF + t0 + tl];
      d_lds[c][tl] = dmod[(b * CPD + c) * NF + t0 + tl];
    }
    __syncthreads();
    if (tid < 64) {
      const int c = tid;
      for (int tl = 0; tl < 128; ++tl) {
        float d = dbase - fabsf(d_lds[c][tl]);
        d = fminf(fmaxf(d, 0.f), 1.f);
        float f = f_lds[c][tl];
        float out = (ch == 0 && tl == 0) ? f : (f + carry) * d;
        carry = out;
        damped_t[(b * NF + t0 + tl) * CPD + c] = out;
      }
    }
  }
}

// ---------------------------------------------------------------------------
// K2: hypernetwork + routing einsum + to_ctrl (unchanged)
// ---------------------------------------------------------------------------
__global__ __launch_bounds__(256) void k_hyper(const float* __restrict__ damped_t,
                                               const float* __restrict__ routing,
                                               const float* __restrict__ W1,
                                               const float* __restrict__ b1,
                                               const float* __restrict__ W2,
                                               const float* __restrict__ b2,
                                               const float* __restrict__ to_control,
                                               float* __restrict__ routed,
                                               float* __restrict__ to_ctrl) {
  __shared__ float xs[4][64];
  __shared__ float hs[4][16];
  __shared__ float rs[4][64];
  const int blk = blockIdx.x;
  const int b = blk >> 7;
  const int t0 = (blk & 127) * 4;
  const int lt = threadIdx.x >> 6;
  const int d = threadIdx.x & 63;
  const int t = t0 + lt;

  xs[lt][d] = damped_t[(b * NF + t) * CPD + d];
  __syncthreads();
  if (d < HID) {
    float a = b1[d];
    for (int c = 0; c < CPD; ++c) a = fmaf(xs[lt][c], W1[c * HID + d], a);
    hs[lt][d] = a > 0.f ? a : 0.2f * a;
  }
  __syncthreads();
  float hreg[HID];
#pragma unroll
  for (int j = 0; j < HID; ++j) hreg[j] = hs[lt][j];

  float acc = 0.f;
  for (int c = 0; c < CPD; ++c) {
    float w = routing[c * RES + d] + b2[c * RES + d];
    const float* w2p = W2 + c * RES + d;
#pragma unroll
    for (int j = 0; j < HID; ++j) w = fmaf(hreg[j], w2p[j * (CPD * RES)], w);
    acc = fmaf(xs[lt][c], w, acc);
  }
  routed[(b * RES + d) * NF + t] = acc;
  rs[lt][d] = acc;
  __syncthreads();
  float tc = 0.f;
  for (int q = 0; q < RES; ++q) tc = fmaf(rs[lt][q], to_control[q * CPD + d], tc);
  to_ctrl[(b * CPD + d) * NF + t] = tc;
}

// ---------------------------------------------------------------------------
// K3: block-Hankel GEMM conv, round-4: single-term f16 (e scaled by 2^10).
// 512 threads (8 waves) x 4 tiles/wave = 32768 outputs/block, 2 blocks/CU.
// er: reversed energy f16, XOR-swizzled 16B granules sig(g)=g^((g>>3)&7).
// fcp: filter f16 tap-pairs, 2 parity copies -> B fragment loads with ZERO
//      shuffle ops (4 dwords -> f16x8 directly).
// Per tile-step: 1 ds_read_b128 (A) + 1 MFMA. B shared across 4 tiles.
// ---------------------------------------------------------------------------
#define ER_N 34832          // staged samples (= 8 * 4354)
#define ER_G 4360           // granule alloc incl swizzle round-up
#define FCP_DW 1072         // dwords per parity copy

__global__ __launch_bounds__(512, 4) void k_conv(const float* __restrict__ routed,
                                                 const float* __restrict__ noise,
                                                 const float* __restrict__ filters,
                                                 float* __restrict__ outp) {
  __shared__ __align__(16) unsigned short er[ER_G * 8];
  __shared__ __align__(16) unsigned fcp[2 * FCP_DW];

  const int tid = threadIdx.x;
  const int seg = blockIdx.x & 3;
  const int r = (blockIdx.x >> 2) & 63;
  const int b = blockIdx.x >> 8;
  const int NB = seg * 32768;
  const int E0 = NB + 32776;          // er[x] = e[E0 - x] * 1024 (f16)
  const int chan = b * RES + r;
  const float* rp = routed + chan * NF;
  const float* npz = noise + (size_t)chan * NS;

  // ---- filter staging: copy p dword q = f16 taps (2q+p-40, 2q+p-39) ----
  for (int idx = tid; idx < 2 * FCP_DW; idx += 512) {
    int p = idx >= FCP_DW;
    int q = idx - p * FCP_DW;
    int t0 = 2 * q + p - 40;
    float f0 = (t0 >= 0 && t0 < FS) ? filters[r * FS + t0] : 0.f;
    float f1 = (t0 + 1 >= 0 && t0 + 1 < FS) ? filters[r * FS + t0 + 1] : 0.f;
    union { _Float16 h[2]; unsigned u; } P;
    P.h[0] = (_Float16)f0;
    P.h[1] = (_Float16)f1;
    fcp[idx] = P.u;
  }

  // ---- energy staging: pairs, f16*1024, XOR-swizzled granule layout ----
  unsigned* er32 = (unsigned*)er;
  for (int x2 = tid; x2 < ER_N / 2; x2 += 512) {
    int x = 2 * x2;
    union { _Float16 h[2]; unsigned u; } P;
#pragma unroll
    for (int k = 0; k < 2; ++k) {
      int n = E0 - x - k;
      float e = 0.f;
      if (n >= 0 && n < NS) {
        float pos = ((float)n + 0.5f) * (1.f / 256.f) - 0.5f;
        pos = fminf(fmaxf(pos, 0.f), 511.f);
        float fi = floorf(pos);
        int i0 = (int)fi;
        int i1 = min(i0 + 1, 511);
        float fr = pos - fi;
        float u = rp[i0] * (1.f - fr) + rp[i1] * fr;
        e = u * npz[n];
      }
      P.h[k] = (_Float16)(e * 1024.f);
    }
    int g = x >> 3;
    int sig = g ^ ((g >> 3) & 7);
    er32[sig * 4 + ((x & 7) >> 1)] = P.u;
  }
  __syncthreads();

  const int w = tid >> 6;
  const int l = tid & 63;
  const int row = l & 31;   // A-row == B-col lane index
  const int h = l >> 5;     // k-half

  // A granule base per tile: g = 4092 - 128*T - 4*row + h + 2*s, T = 4w+tau
  const int gb0 = 4092 - 512 * w - 4 * row + h;
  // B dword base: taps row+8h+16s-40.. -> copy p=row&1, q0 = (row>>1)+4h+8s
  int qB = (row >> 1) + 4 * h + (row & 1) * FCP_DW;

  f32x16 acc0, acc1, acc2, acc3;
#pragma unroll
  for (int i = 0; i < 16; ++i) { acc0[i] = 0.f; acc1[i] = 0.f; acc2[i] = 0.f; acc3[i] = 0.f; }

  for (int s = 0; s < 131; ++s) {
    union { unsigned u[4]; f16x8 v; } Bf;
    Bf.u[0] = fcp[qB];
    Bf.u[1] = fcp[qB + 1];
    Bf.u[2] = fcp[qB + 2];
    Bf.u[3] = fcp[qB + 3];
    const int s2 = 2 * s;
#define TILE(ACC, GB)                                                         \
    {                                                                         \
      int g = (GB) + s2;                                                      \
      int ab = (g ^ ((g >> 3) & 7)) << 4;                                     \
      union { uint4 u; f16x8 v; } Af;                                         \
      Af.u = *(const uint4*)((const char*)er + ab);                           \
      ACC = __builtin_amdgcn_mfma_f32_32x32x16_f16(Af.v, Bf.v, ACC, 0, 0, 0); \
    }
    TILE(acc0, gb0)
    TILE(acc1, gb0 - 128)
    TILE(acc2, gb0 - 256)
    TILE(acc3, gb0 - 384)
#undef TILE
    qB += 8;
  }

  // ---- C store: col = row-lane, crow = (rg&3) + 8*(rg>>2) + 4*h; /1024 ----
  float* base = outp + (size_t)chan * NS + NB;
#define STORE(ACC, TAU)                                                       \
  {                                                                           \
    float* po = base + 1024 * (4 * w + (TAU));                                \
    _Pragma("unroll")                                                         \
    for (int rg = 0; rg < 16; ++rg) {                                         \
      int crow = (rg & 3) + 8 * (rg >> 2) + 4 * h;                            \
      po[32 * crow + row] = ACC[rg] * (1.f / 1024.f);                         \
    }                                                                         \
  }
  STORE(acc0, 0)
  STORE(acc1, 1)
  STORE(acc2, 2)
  STORE(acc3, 3)
#undef STORE
}

// ---------------------------------------------------------------------------
extern "C" void kernel_launch(void* const* d_in, const int* in_sizes, int n_in,
                              void* d_out, int out_size, void* d_ws, size_t ws_size,
                              hipStream_t stream) {
  const float* forces     = (const float*)d_in[0];
  const float* dmod       = (const float*)d_in[1];
  const float* noise      = (const float*)d_in[2];
  const float* dparam     = (const float*)d_in[3];
  const float* routing    = (const float*)d_in[4];
  const float* W1         = (const float*)d_in[5];
  const float* b1         = (const float*)d_in[6];
  const float* W2         = (const float*)d_in[7];
  const float* b2         = (const float*)d_in[8];
  const float* filters    = (const float*)d_in[9];
  const float* to_control = (const float*)d_in[10];

  float* out = (float*)d_out;
  float* to_ctrl = out;                                  // (B,CPD,NF)
  float* reso = out + BATCH * CPD * NF;                  // (B,RES,NS)

  float* damped_t = (float*)d_ws;                        // (B,NF,CPD)
  float* routed = damped_t + BATCH * NF * CPD;           // (B,RES,NF)

  k_scan<<<BATCH, 256, 0, stream>>>(forces, dmod, dparam, damped_t);
  k_hyper<<<BATCH * NF / 4, 256, 0, stream>>>(damped_t, routing, W1, b1, W2, b2,
                                              to_control, routed, to_ctrl);
  k_conv<<<BATCH * RES * (NS / 32768), 512, 0, stream>>>(routed, noise, filters, reso);
}